// Round 11
// baseline (28.875 us; speedup 1.0000x reference)
//
#include <hip/hip_runtime.h>

// Problem constants (fixed by reference setup_inputs): D=32 detectors,
// in_s = out_s = 64, row stride 2048 floats, B = 8192.
#define NDET    32
#define SEG     64
#define ROWLEN  2048
#define TILE_B  128
#define NITER   4              // tiles per block; block covers 512 rows
#define THREADS 256
#define XSTR    72             // x LDS row stride, bf16 (144B, padded)
#define YSTR    68             // y LDS row stride, f32 (272B, padded)

typedef __bf16 bf16x8 __attribute__((ext_vector_type(8)));
typedef __bf16 bf16x4 __attribute__((ext_vector_type(4)));
typedef float  f32x4  __attribute__((ext_vector_type(4)));

__device__ __forceinline__ bf16x4 cvt4(f32x4 a) {
  bf16x4 r;
  r[0] = (__bf16)a[0]; r[1] = (__bf16)a[1]; r[2] = (__bf16)a[2]; r[3] = (__bf16)a[3];
  return r;
}

__device__ __forceinline__ bf16x8 cvt8(f32x4 a, f32x4 b) {
  bf16x8 r;
  r[0] = (__bf16)a[0]; r[1] = (__bf16)a[1]; r[2] = (__bf16)a[2]; r[3] = (__bf16)a[3];
  r[4] = (__bf16)b[0]; r[5] = (__bf16)b[1]; r[6] = (__bf16)b[2]; r[7] = (__bf16)b[3];
  return r;
}

// y[b, d*64+o] = sum_i x[b, d*64+i] * W[d*64+o, d*64+i]
//
// v11 = v9 (LDS output transpose) x v7 (multi-tile depth-2 reg prefetch),
// ZERO barriers: W frags in registers, so both LDS regions are wave-private
// (wave wid: x rows wid*32..+31 of xls; y rows wid*16..+15 of yls) and
// ordering is intra-wave s_waitcnt lgkmcnt(0) only. Loads for tiles t+1,t+2
// stay in flight while tile t computes/stores; global stores drain in
// background. Every global access is a coalesced 256B-per-16-lane window.
__global__ __launch_bounds__(THREADS) void ensemble_linear_v11(
    const float* __restrict__ x, const float* __restrict__ W,
    float* __restrict__ y) {
  const int d     = blockIdx.y;
  const int b0    = blockIdx.x * (TILE_B * NITER);
  const int t     = threadIdx.x;
  const int lane  = t & 63;
  const int wid   = t >> 6;        // 0..3
  const int dbase = d * SEG;

  const int rq  = lane >> 4;       // staging: row within 4-row quad
  const int c4  = lane & 15;       // staging: 16B chunk within 256B row
  const int m16 = lane & 15;       // fragment M/N index
  const int kg  = lane >> 4;       // fragment k-group

  __shared__ __bf16 xls[TILE_B * XSTR];   // 18432 B; wave-private 32-row slices
  __shared__ float  yls[64 * YSTR];       // 17408 B; wave-private 16-row slices

  const int srow = wid * 32 + rq;  // staging row base (+p*4)
  const float* xbase = x + (size_t)(b0 + srow) * ROWLEN + dbase + c4 * 4;

  // ---- prologue: issue x loads for tiles 0 and 1 (8 KB/wave in flight) ----
  f32x4 xv[2][8];
#pragma unroll
  for (int p = 0; p < 8; ++p)
    xv[0][p] = *(const f32x4*)(xbase + (size_t)(p * 4) * ROWLEN);
#pragma unroll
  for (int p = 0; p < 8; ++p)
    xv[1][p] = *(const f32x4*)(xbase + (size_t)(TILE_B + p * 4) * ROWLEN);

  // ---- W fragments direct to registers (L2-hot; once per block) ----
  bf16x8 wfrag[4][2];
#pragma unroll
  for (int g = 0; g < 4; ++g) {
    const float* wp = W + (size_t)(dbase + g * 16 + m16) * ROWLEN + dbase + kg * 8;
    f32x4 wa0 = *(const f32x4*)(wp);
    f32x4 wa1 = *(const f32x4*)(wp + 4);
    f32x4 wb0 = *(const f32x4*)(wp + 32);
    f32x4 wb1 = *(const f32x4*)(wp + 36);
    wfrag[g][0] = cvt8(wa0, wa1);
    wfrag[g][1] = cvt8(wb0, wb1);
  }

  // ---- pipelined tile loop (fully unrolled; xv index static) ----
#pragma unroll
  for (int tt = 0; tt < NITER; ++tt) {
    const int cur = tt & 1;

    // stage tile tt (compiler inserts vmcnt waits for xv[cur])
#pragma unroll
    for (int p = 0; p < 8; ++p)
      *(bf16x4*)(&xls[(srow + p * 4) * XSTR + c4 * 4]) = cvt4(xv[cur][p]);

    // prefetch tile tt+2 into the freed register buffer
    if (tt + 2 < NITER) {
#pragma unroll
      for (int p = 0; p < 8; ++p)
        xv[cur][p] = *(const f32x4*)(xbase + (size_t)((tt + 2) * TILE_B + p * 4) * ROWLEN);
    }

    // our ds_writes retired before our ds_reads issue (wave-private)
    asm volatile("s_waitcnt lgkmcnt(0)" ::: "memory");
    __builtin_amdgcn_sched_barrier(0);

    // ---- per 16-row subtile: MFMA -> yls -> coalesced store ----
#pragma unroll
    for (int s = 0; s < 2; ++s) {
      const int rbase = wid * 32 + s * 16;
      bf16x8 a0 = *(const bf16x8*)(&xls[(rbase + m16) * XSTR + kg * 8]);       // k 0..31
      bf16x8 a1 = *(const bf16x8*)(&xls[(rbase + m16) * XSTR + 32 + kg * 8]);  // k 32..63

      // yls wave region rows wid*16..+15; prior subtile's ds_reads are
      // retired before these writes (in-order DS pipe + lgkm below).
#pragma unroll
      for (int g = 0; g < 4; ++g) {
        f32x4 acc = (f32x4){0.f, 0.f, 0.f, 0.f};
        acc = __builtin_amdgcn_mfma_f32_16x16x32_bf16(wfrag[g][0], a0, acc, 0, 0, 0);
        acc = __builtin_amdgcn_mfma_f32_16x16x32_bf16(wfrag[g][1], a1, acc, 0, 0, 0);
        *(f32x4*)(&yls[(wid * 16 + m16) * YSTR + g * 16 + kg * 4]) = acc;
      }

      asm volatile("s_waitcnt lgkmcnt(0)" ::: "memory");
      __builtin_amdgcn_sched_barrier(0);

      // coalesced store: 16-lane group = one complete 256B row window
#pragma unroll
      for (int p = 0; p < 4; ++p) {
        const int rl = p * 4 + rq;   // row within subtile
        f32x4 v = *(const f32x4*)(&yls[(wid * 16 + rl) * YSTR + c4 * 4]);
        *(f32x4*)(y + (size_t)(b0 + tt * TILE_B + rbase + rl) * ROWLEN + dbase + c4 * 4) = v;
      }
    }
  }
}

extern "C" void kernel_launch(void* const* d_in, const int* in_sizes, int n_in,
                              void* d_out, int out_size, void* d_ws, size_t ws_size,
                              hipStream_t stream) {
  const float* x = (const float*)d_in[0];
  const float* W = (const float*)d_in[1];
  float* y = (float*)d_out;
  const int B = in_sizes[0] / ROWLEN;   // 8192
  dim3 grid(B / (TILE_B * NITER), NDET);
  ensemble_linear_v11<<<grid, dim3(THREADS), 0, stream>>>(x, W, y);
}

// Round 12
// 26.562 us; speedup vs baseline: 1.0871x; 1.0871x over previous
//
#include <hip/hip_runtime.h>

// Problem constants (fixed by reference setup_inputs): D=32 detectors,
// in_s = out_s = 64, row stride 2048 floats, B = 8192.
#define NDET    32
#define SEG     64
#define ROWLEN  2048
#define TILE_B  128
#define THREADS 256
#define XSTR    72   // x LDS row stride, bf16 (144B, 16B-aligned, padded)
#define WSTR    72   // W LDS row stride, bf16
#define YSTR    68   // y LDS row stride, f32 (272B, 16B-aligned, padded)

typedef __bf16 bf16x8 __attribute__((ext_vector_type(8)));
typedef __bf16 bf16x4 __attribute__((ext_vector_type(4)));
typedef float  f32x4  __attribute__((ext_vector_type(4)));

__device__ __forceinline__ bf16x4 cvt4(f32x4 a) {
  bf16x4 r;
  r[0] = (__bf16)a[0]; r[1] = (__bf16)a[1]; r[2] = (__bf16)a[2]; r[3] = (__bf16)a[3];
  return r;
}

// y[b, d*64+o] = sum_i x[b, d*64+i] * W[d*64+o, d*64+i]
//
// v12 = v9 (best, 26.9us) + ONE variable: nontemporal y stores.
// v9's stores are full 256B-contiguous windows per 16-lane group (complete
// 128B cache lines), so nt cannot amplify (r5's 80MB came from scattered
// 64B chunks). Mechanism under test: the 67MB y write stream write-allocates
// in L2/L3 and evicts x's prior-replay residency DURING the dispatch; nt
// streams y past the caches, protecting x -> read stream shifts HBM->L3.
// Diagnostic signature: FETCH_SIZE 35MB -> 10-20MB, WRITE_SIZE unchanged.
__global__ __launch_bounds__(THREADS) void ensemble_linear_v12(
    const float* __restrict__ x, const float* __restrict__ W,
    float* __restrict__ y) {
  const int d     = blockIdx.y;
  const int b0    = blockIdx.x * TILE_B;
  const int t     = threadIdx.x;
  const int lane  = t & 63;
  const int wid   = t >> 6;        // 0..3
  const int dbase = d * SEG;

  const int rq  = lane >> 4;       // staging: row within 4-row quad
  const int c4  = lane & 15;       // staging: 16B chunk within 256B row
  const int m16 = lane & 15;       // fragment M/N index
  const int kg  = lane >> 4;       // fragment k-group

  __shared__ __align__(16) unsigned char smem[TILE_B * YSTR * 4];  // 34816B
  __bf16* xls = (__bf16*)smem;                        // [128][XSTR]
  __bf16* wls = (__bf16*)(smem + TILE_B * XSTR * 2);  // [64][WSTR]
  float*  yls = (float*)smem;                         // [128][YSTR] (phase B)

  // ---- issue x loads (coalesced: 4 complete 256B row windows / instr) ----
  f32x4 xv[8];
#pragma unroll
  for (int p = 0; p < 8; ++p) {
    const int row = wid * 32 + p * 4 + rq;
    xv[p] = *(const f32x4*)(x + (size_t)(b0 + row) * ROWLEN + dbase + c4 * 4);
  }

  // ---- issue W loads (same coalesced mapping; L2-hot) ----
  f32x4 wv[4];
#pragma unroll
  for (int p = 0; p < 4; ++p) {
    const int o = wid * 16 + p * 4 + rq;
    wv[p] = *(const f32x4*)(W + (size_t)(dbase + o) * ROWLEN + dbase + c4 * 4);
  }

  // ---- stage to LDS (bf16) ----
#pragma unroll
  for (int p = 0; p < 8; ++p) {
    const int row = wid * 32 + p * 4 + rq;
    *(bf16x4*)(&xls[row * XSTR + c4 * 4]) = cvt4(xv[p]);
  }
#pragma unroll
  for (int p = 0; p < 4; ++p) {
    const int o = wid * 16 + p * 4 + rq;
    *(bf16x4*)(&wls[o * WSTR + c4 * 4]) = cvt4(wv[p]);
  }

  __syncthreads();   // barrier 1: tiles staged

  // ---- fragment reads (ALL LDS reads happen before barrier 2) ----
  bf16x8 wfrag[4][2];
#pragma unroll
  for (int g = 0; g < 4; ++g)
#pragma unroll
    for (int kh = 0; kh < 2; ++kh)
      wfrag[g][kh] = *(const bf16x8*)(&wls[(g * 16 + m16) * WSTR + kh * 32 + kg * 8]);

  bf16x8 afrag[2][2];   // [s][kh]; wave owns rows [wid*32, wid*32+32)
#pragma unroll
  for (int s = 0; s < 2; ++s) {
    const int rbase = wid * 32 + s * 16;
    afrag[s][0] = *(const bf16x8*)(&xls[(rbase + m16) * XSTR + kg * 8]);
    afrag[s][1] = *(const bf16x8*)(&xls[(rbase + m16) * XSTR + 32 + kg * 8]);
  }

  __syncthreads();   // barrier 2: safe to overlay y onto x/W region

  // ---- MFMA + scatter accs to LDS y-tile (wave-private rows) ----
  // Swapped-operand MFMA (r3-verified): D = W_tile . x_tile^T.
#pragma unroll
  for (int s = 0; s < 2; ++s) {
    const int rbase = wid * 32 + s * 16;
#pragma unroll
    for (int g = 0; g < 4; ++g) {
      f32x4 acc = (f32x4){0.f, 0.f, 0.f, 0.f};
      acc = __builtin_amdgcn_mfma_f32_16x16x32_bf16(wfrag[g][0], afrag[s][0], acc, 0, 0, 0);
      acc = __builtin_amdgcn_mfma_f32_16x16x32_bf16(wfrag[g][1], afrag[s][1], acc, 0, 0, 0);
      *(f32x4*)(&yls[(rbase + m16) * YSTR + g * 16 + kg * 4]) = acc;
    }
  }

  // Wave-private region: our ds_writes retired before our ds_reads issue.
  asm volatile("s_waitcnt lgkmcnt(0)" ::: "memory");
  __builtin_amdgcn_sched_barrier(0);

  // ---- coalesced NONTEMPORAL y store: 16-lane group = one full 256B window ----
#pragma unroll
  for (int p = 0; p < 8; ++p) {
    const int row = wid * 32 + p * 4 + rq;
    f32x4 v = *(const f32x4*)(&yls[row * YSTR + c4 * 4]);
    __builtin_nontemporal_store(v,
        (f32x4*)(y + (size_t)(b0 + row) * ROWLEN + dbase + c4 * 4));
  }
}

extern "C" void kernel_launch(void* const* d_in, const int* in_sizes, int n_in,
                              void* d_out, int out_size, void* d_ws, size_t ws_size,
                              hipStream_t stream) {
  const float* x = (const float*)d_in[0];
  const float* W = (const float*)d_in[1];
  float* y = (float*)d_out;
  const int B = in_sizes[0] / ROWLEN;   // 8192
  dim3 grid(B / TILE_B, NDET);
  ensemble_linear_v12<<<grid, dim3(THREADS), 0, stream>>>(x, W, y);
}